// Round 2
// baseline (335.827 us; speedup 1.0000x reference)
//
#include <hip/hip_runtime.h>
#include <math.h>

// ---------------------------------------------------------------------------
// AttentionNet weighted-anchor aggregator.
//   x:  (8, 448, 448, 3) f32
//   wp3:(8, 6, 4, 14, 14) f32   wp4:(8, 6, 4, 7, 7) f32   wp5:(8, 9, 4, 4, 4) f32
//   out:(32, 224, 224, 3) f32 = sum over 21 configs of
//        resize_bilinear( einsum('bkij,bihjwc->bkhwc', w, patches), 224,224 )
//
// Phase 0a: init_tables — normalized zero-padded 4-tap weights + i0.
// Phase 0b: transpose_w — weights to [cfg][b][grid][k0..k3] float4.
// Phase A : agg_all — ONE dispatch; branch-free inner loop (clamped dwordx3
//           loads + cndmask). IMAGE-PER-XCD decomposition: b = local & 7 so
//           (under round-robin block->XCD dispatch, BATCH==8==XCDs) each XCD
//           touches exactly one 2.4MB image -> x stays in its 4MB L2.
//           agg rows padded to even width (kwp); epilogue stores one aligned
//           uint4 (2 px bf16x3) per k.
// Phase B : resize_kernel — 2x2 output px per thread, barrier-free. Tap rows
//           fetched as 16B uint4 pair-loads (NR rows x NP pairs per cfg);
//           weights pre-shifted into static arrays (cndmask chains, no
//           dynamic indexing) so clamped/padded pixels get exact-0 weights.
//           1D grid + chunked XCD swizzle (4 bk planes per XCD chunk).
// ---------------------------------------------------------------------------

#define BATCH 8
#define KK 4
#define OUT_HW 224
#define IMG_HW 448
#define NCFG 21

#define WTBL_BYTES (NCFG * 2 * OUT_HW * 16)     // 150528
#define ITBL_BYTES (NCFG * 2 * OUT_HW * 4)      // 37632
#define WT_OFF_BYTES (WTBL_BYTES + ITBL_BYTES)  // 188160
#define WT_F4 12912                             // 8 * (6*196 + 6*49 + 9*16)
#define AGG_OFF_BYTES (WT_OFF_BYTES + WT_F4 * 16)  // 394752 (16B aligned)

#define RZ_BLOCKS (7 * 7 * BATCH * KK)          // 1568
#define RZ_CHUNK (RZ_BLOCKS / 8)                // 196

struct CfgEntry {          // resize view of a config
    int kh, kw, kwp;
    int mth, mtw;          // max tap count per dim (2..4)
    int tbl;               // global cfg index (table lookup)
    int ws_off;            // px (uint2) offset in agg region
};

struct GroupArgs {
    CfgEntry e[NCFG];
    int n;
};

struct ACfg {              // agg view of a config
    int kh, kw, kwp, p0, p1;
    int layer;             // 0=p3, 1=p4, 2=p5
    int qpr;               // pairs (2px) per row = kwp/2
    int wt_off;            // float4 offset of transposed weights
    int ws_off;            // px offset in agg region
    int block_start;
    int blocks_per_img;    // ceil(kh*qpr/256)
};

struct AggArgs {
    ACfg e[NCFG];
    int n;
};

struct TablesArgs { int kh[NCFG]; int kw[NCFG]; };

struct TrArgs {
    int layer[NCFG];
    int anchor[NCFG];
    int gsz[NCFG];
    int wt_off[NCFG];
};

struct F3 { float a, b, c; };

__device__ inline unsigned int bf16_rne(float f) {
    unsigned int u = __float_as_uint(f);
    return (u + 0x7fffu + ((u >> 16) & 1u)) >> 16;
}

// ---------------------------------------------------------------------------
// Phase 0a: tap tables. jax.image.resize('bilinear', antialias=True):
//   inv=in/out; ks=max(inv,1); sf=(o+0.5)*inv-0.5; taps i in
//   [ceil(sf-ks), floor(sf+ks)] clamped, w=max(0,1-|i-sf|/ks) normalized.
// ---------------------------------------------------------------------------
__global__ __launch_bounds__(256) void init_tables(float4* __restrict__ wtbl,
                                                   int* __restrict__ itbl,
                                                   TablesArgs t) {
    int cfg = blockIdx.x >> 1;
    int dim = blockIdx.x & 1;
    int o = threadIdx.x;
    if (o >= OUT_HW) return;
    int n = dim ? t.kw[cfg] : t.kh[cfg];

    float inv = (float)(1.0 / ((double)OUT_HW / (double)n));
    float ks  = inv > 1.f ? inv : 1.f;
    float rks = 1.f / ks;
    float sf  = ((float)o + 0.5f) * inv - 0.5f;
    int i0 = (int)ceilf(sf - ks);  if (i0 < 0) i0 = 0;
    int i1 = (int)floorf(sf + ks); if (i1 > n - 1) i1 = n - 1;
    float sum = 0.f;
    for (int i = i0; i <= i1; ++i) {
        float v = 1.f - fabsf((float)i - sf) * rks;
        sum += (v > 0.f ? v : 0.f);
    }
    float rsum = 1.f / sum;
    float w[4];
#pragma unroll
    for (int d = 0; d < 4; ++d) {
        int i = i0 + d;
        float v = 0.f;
        if (i <= i1) {
            v = 1.f - fabsf((float)i - sf) * rks;
            v = (v > 0.f ? v : 0.f) * rsum;
        }
        w[d] = v;
    }
    int idx = cfg * (2 * OUT_HW) + dim * OUT_HW + o;
    wtbl[idx] = make_float4(w[0], w[1], w[2], w[3]);
    itbl[idx] = i0;
}

// ---------------------------------------------------------------------------
// Phase 0b: transpose weights (B,A,K,gh,gw) -> per cfg [b][g][k0..k3] float4.
// ---------------------------------------------------------------------------
__global__ __launch_bounds__(256) void transpose_w(
        const float* __restrict__ wp3, const float* __restrict__ wp4,
        const float* __restrict__ wp5, float4* __restrict__ wT, TrArgs t) {
    int cfg = blockIdx.x;
    int b = blockIdx.y;
    int gsz = t.gsz[cfg];
    const float* base;
    int A;
    if (t.layer[cfg] == 0)      { base = wp3; A = 6; }
    else if (t.layer[cfg] == 1) { base = wp4; A = 6; }
    else                        { base = wp5; A = 9; }
    const float* src = base + (size_t)(b * A + t.anchor[cfg]) * (KK * gsz);
    for (int g = threadIdx.x; g < gsz; g += 256) {
        wT[t.wt_off[cfg] + b * gsz + g] =
            make_float4(src[0 * gsz + g], src[1 * gsz + g],
                        src[2 * gsz + g], src[3 * gsz + g]);
    }
}

// ---------------------------------------------------------------------------
// Agg body (templated): 2 consecutive px per thread, acc[2][4][3].
// Branch-free: clamped dwordx3 loads always issue; invalid px zeroed by
// cndmask. Row validity handled by the i-loop bounds (no per-iter cost).
// ---------------------------------------------------------------------------
template <int GH, int GW, int STRIDE>
__device__ inline void agg_body(const ACfg& c, int b, int h, int w0,
                                const float* __restrict__ xb,
                                const float4* __restrict__ wlds,
                                uint2* __restrict__ agg) {
    float acc[2][4][3] = {};

    const int rb = h - c.p0;
    // valid i range: 0 <= rb + i*STRIDE <= IMG_HW-1
    int ilo = rb >= 0 ? 0 : (-rb + STRIDE - 1) / STRIDE;
    int ihi = (IMG_HW - 1 - rb) / STRIDE;
    if (ihi > GH - 1) ihi = GH - 1;

    const int cb = w0 - c.p1;

#pragma unroll 1
    for (int i = ilo; i <= ihi; ++i) {
        const float* xr = xb + (size_t)(rb + i * STRIDE) * (IMG_HW * 3);
        const float4* wrow = wlds + i * GW;
#pragma unroll
        for (int j = 0; j < GW; ++j) {
            int col = cb + j * STRIDE;
            int cc0 = col;
            if (cc0 < 0) cc0 = 0;
            if (cc0 > IMG_HW - 1) cc0 = IMG_HW - 1;
            int cc1 = col + 1;
            if (cc1 < 0) cc1 = 0;
            if (cc1 > IMG_HW - 1) cc1 = IMG_HW - 1;
            F3 v0 = *(const F3*)(xr + (size_t)cc0 * 3);
            F3 v1 = *(const F3*)(xr + (size_t)cc1 * 3);
            bool k0 = (unsigned)col < (unsigned)IMG_HW;
            bool k1 = (unsigned)(col + 1) < (unsigned)IMG_HW;
            float x0 = k0 ? v0.a : 0.f;
            float x1 = k0 ? v0.b : 0.f;
            float x2 = k0 ? v0.c : 0.f;
            float y0 = k1 ? v1.a : 0.f;
            float y1 = k1 ? v1.b : 0.f;
            float y2 = k1 ? v1.c : 0.f;
            float4 wk = wrow[j];   // uniform address -> broadcast b128
            acc[0][0][0] = fmaf(wk.x, x0, acc[0][0][0]);
            acc[0][0][1] = fmaf(wk.x, x1, acc[0][0][1]);
            acc[0][0][2] = fmaf(wk.x, x2, acc[0][0][2]);
            acc[0][1][0] = fmaf(wk.y, x0, acc[0][1][0]);
            acc[0][1][1] = fmaf(wk.y, x1, acc[0][1][1]);
            acc[0][1][2] = fmaf(wk.y, x2, acc[0][1][2]);
            acc[0][2][0] = fmaf(wk.z, x0, acc[0][2][0]);
            acc[0][2][1] = fmaf(wk.z, x1, acc[0][2][1]);
            acc[0][2][2] = fmaf(wk.z, x2, acc[0][2][2]);
            acc[0][3][0] = fmaf(wk.w, x0, acc[0][3][0]);
            acc[0][3][1] = fmaf(wk.w, x1, acc[0][3][1]);
            acc[0][3][2] = fmaf(wk.w, x2, acc[0][3][2]);
            acc[1][0][0] = fmaf(wk.x, y0, acc[1][0][0]);
            acc[1][0][1] = fmaf(wk.x, y1, acc[1][0][1]);
            acc[1][0][2] = fmaf(wk.x, y2, acc[1][0][2]);
            acc[1][1][0] = fmaf(wk.y, y0, acc[1][1][0]);
            acc[1][1][1] = fmaf(wk.y, y1, acc[1][1][1]);
            acc[1][1][2] = fmaf(wk.y, y2, acc[1][1][2]);
            acc[1][2][0] = fmaf(wk.z, y0, acc[1][2][0]);
            acc[1][2][1] = fmaf(wk.z, y1, acc[1][2][1]);
            acc[1][2][2] = fmaf(wk.z, y2, acc[1][2][2]);
            acc[1][3][0] = fmaf(wk.w, y0, acc[1][3][0]);
            acc[1][3][1] = fmaf(wk.w, y1, acc[1][3][1]);
            acc[1][3][2] = fmaf(wk.w, y2, acc[1][3][2]);
        }
    }

    const int npix = c.kh * c.kwp;
#pragma unroll
    for (int k = 0; k < 4; ++k) {
        size_t base = (size_t)c.ws_off + (size_t)(b * KK + k) * npix
                    + (size_t)h * c.kwp + w0;
        uint4 o;
        o.x = bf16_rne(acc[0][k][0]) | (bf16_rne(acc[0][k][1]) << 16);
        o.y = bf16_rne(acc[0][k][2]);
        o.z = bf16_rne(acc[1][k][0]) | (bf16_rne(acc[1][k][1]) << 16);
        o.w = bf16_rne(acc[1][k][2]);
        *(uint4*)(agg + base) = o;   // base even -> 16B aligned
    }
}

// ---------------------------------------------------------------------------
// Phase A: one dispatch for all configs; block-uniform layer switch.
// b = local & 7: with round-robin block->XCD dispatch and 8 images == 8 XCDs,
// each XCD only ever touches one image (block_start is always 8-aligned since
// every cfg contributes blocks_per_img*8 blocks).
// ---------------------------------------------------------------------------
__global__ __launch_bounds__(256, 4) void agg_all(
        const float* __restrict__ x,
        const float4* __restrict__ wT,
        uint2* __restrict__ agg,
        AggArgs a) {
    int bid = blockIdx.x;
    int ci = 0;
    while (ci + 1 < a.n && bid >= a.e[ci + 1].block_start) ci++;
    const ACfg c = a.e[ci];
    int local = bid - c.block_start;
    int b     = local & 7;           // image-per-XCD
    int sblk  = local >> 3;

    const int gsz = (c.layer == 0) ? 196 : (c.layer == 1) ? 49 : 16;
    __shared__ float4 wlds[196];
    for (int t = threadIdx.x; t < gsz; t += 256)
        wlds[t] = wT[c.wt_off + b * gsz + t];
    __syncthreads();

    int pidx = sblk * 256 + (int)threadIdx.x;
    if (pidx >= c.kh * c.qpr) return;
    int h  = pidx / c.qpr;
    int w0 = (pidx - h * c.qpr) * 2;

    const float* __restrict__ xb = x + (size_t)b * (IMG_HW * IMG_HW * 3);
    if (c.layer == 0)      agg_body<14, 14, 32>(c, b, h, w0, xb, wlds, agg);
    else if (c.layer == 1) agg_body<7, 7, 64>(c, b, h, w0, xb, wlds, agg);
    else                   agg_body<4, 4, 128>(c, b, h, w0, xb, wlds, agg);
}

// ---------------------------------------------------------------------------
// Resize tap micro-kernel for a 2x2 output-px quad. NR rows x NP uint4
// (2 px) loads; weights pre-shifted into statically-indexed arrays so that
// clamped rows/cols and pad pixels carry exact-0 weight.
//   slot m <-> col a0+m,  wa[m] = wwa[m-d0],  wb[m] = wwb[m-dj]
//   row d  <-> row i0a+d, ra[d] = wha[d],     rb[d] = whb[d-di]
// ---------------------------------------------------------------------------
template <int NR, int NP>
__device__ inline void taps4(const uint2* __restrict__ plane,
                             int kh, int kwp,
                             int i0a, int i0b, int j0a, int j0b,
                             float4 wha, float4 whb,
                             float4 wwa, float4 wwb,
                             float (&acc)[2][2][3]) {
    const int d0 = j0a & 1;
    const int a0 = j0a - d0;
    const int dj = j0b - a0;          // in [0,3]
    const int di = i0b - i0a;         // in [0,2]

    float wa[8], wb[8], ra[8], rb[8];
#pragma unroll
    for (int m = 0; m < 8; ++m) { wa[m] = 0.f; wb[m] = 0.f; ra[m] = 0.f; rb[m] = 0.f; }

    {   // wa = wwa shifted by d0 (0/1)
        bool s = d0 != 0;
        wa[0] = s ? 0.f : wwa.x;
        wa[1] = s ? wwa.x : wwa.y;
        wa[2] = s ? wwa.y : wwa.z;
        wa[3] = s ? wwa.z : wwa.w;
        wa[4] = s ? wwa.w : 0.f;
    }
    {   // wb = wwb shifted by dj (0..3), two-level
        bool s1 = (dj & 1) != 0, s2 = (dj & 2) != 0;
        float t0 = s1 ? 0.f : wwb.x;
        float t1 = s1 ? wwb.x : wwb.y;
        float t2 = s1 ? wwb.y : wwb.z;
        float t3 = s1 ? wwb.z : wwb.w;
        float t4 = s1 ? wwb.w : 0.f;
        wb[0] = s2 ? 0.f : t0;
        wb[1] = s2 ? 0.f : t1;
        wb[2] = s2 ? t0 : t2;
        wb[3] = s2 ? t1 : t3;
        wb[4] = s2 ? t2 : t4;
        wb[5] = s2 ? t3 : 0.f;
        wb[6] = s2 ? t4 : 0.f;
    }
    ra[0] = wha.x; ra[1] = wha.y; ra[2] = wha.z; ra[3] = wha.w;
    {   // rb = whb shifted by di (0..2), two-level
        bool s1 = (di & 1) != 0, s2 = (di & 2) != 0;
        float t0 = s1 ? 0.f : whb.x;
        float t1 = s1 ? whb.x : whb.y;
        float t2 = s1 ? whb.y : whb.z;
        float t3 = s1 ? whb.z : whb.w;
        float t4 = s1 ? whb.w : 0.f;
        rb[0] = s2 ? 0.f : t0;
        rb[1] = s2 ? 0.f : t1;
        rb[2] = s2 ? t0 : t2;
        rb[3] = s2 ? t1 : t3;
        rb[4] = s2 ? t2 : t4;
        rb[5] = s2 ? t3 : 0.f;
        rb[6] = s2 ? t4 : 0.f;
    }

    const int kh1 = kh - 1;
    const int cmax = kwp - 2;
#pragma unroll
    for (int d = 0; d < NR; ++d) {
        int r = i0a + d;
        if (r > kh1) r = kh1;                 // weight is 0 there
        const uint2* rowp = plane + (size_t)r * kwp;
        uint4 v[NP];
#pragma unroll
        for (int p = 0; p < NP; ++p) {
            int cc = a0 + 2 * p;
            if (cc > cmax) cc = cmax;         // weight is 0 there
            v[p] = *(const uint4*)(rowp + cc);
        }
        float ca0 = 0.f, ca1 = 0.f, ca2 = 0.f;
        float cb0 = 0.f, cb1 = 0.f, cb2 = 0.f;
#pragma unroll
        for (int p = 0; p < NP; ++p) {
            float q00 = __uint_as_float(v[p].x << 16);
            float q01 = __uint_as_float(v[p].x & 0xffff0000u);
            float q02 = __uint_as_float(v[p].y << 16);
            float q10 = __uint_as_float(v[p].z << 16);
            float q11 = __uint_as_float(v[p].z & 0xffff0000u);
            float q12 = __uint_as_float(v[p].w << 16);
            float wA0 = wa[2 * p], wA1 = wa[2 * p + 1];
            float wB0 = wb[2 * p], wB1 = wb[2 * p + 1];
            ca0 = fmaf(wA0, q00, ca0); ca0 = fmaf(wA1, q10, ca0);
            ca1 = fmaf(wA0, q01, ca1); ca1 = fmaf(wA1, q11, ca1);
            ca2 = fmaf(wA0, q02, ca2); ca2 = fmaf(wA1, q12, ca2);
            cb0 = fmaf(wB0, q00, cb0); cb0 = fmaf(wB1, q10, cb0);
            cb1 = fmaf(wB0, q01, cb1); cb1 = fmaf(wB1, q11, cb1);
            cb2 = fmaf(wB0, q02, cb2); cb2 = fmaf(wB1, q12, cb2);
        }
        float rA = ra[d], rB = rb[d];
        acc[0][0][0] = fmaf(rA, ca0, acc[0][0][0]);
        acc[0][0][1] = fmaf(rA, ca1, acc[0][0][1]);
        acc[0][0][2] = fmaf(rA, ca2, acc[0][0][2]);
        acc[0][1][0] = fmaf(rA, cb0, acc[0][1][0]);
        acc[0][1][1] = fmaf(rA, cb1, acc[0][1][1]);
        acc[0][1][2] = fmaf(rA, cb2, acc[0][1][2]);
        acc[1][0][0] = fmaf(rB, ca0, acc[1][0][0]);
        acc[1][0][1] = fmaf(rB, ca1, acc[1][0][1]);
        acc[1][0][2] = fmaf(rB, ca2, acc[1][0][2]);
        acc[1][1][0] = fmaf(rB, cb0, acc[1][1][0]);
        acc[1][1][1] = fmaf(rB, cb1, acc[1][1][1]);
        acc[1][1][2] = fmaf(rB, cb2, acc[1][1][2]);
    }
}

// ---------------------------------------------------------------------------
// Phase B: barrier-free resize, 2x2 output px per thread.
// Grid: 1D RZ_BLOCKS with chunked XCD swizzle (each XCD gets 4 bk planes).
// ---------------------------------------------------------------------------
__global__ __launch_bounds__(256) void resize_kernel(
        const uint2* __restrict__ agg,
        const float4* __restrict__ wtbl,
        const int* __restrict__ itbl,
        float* __restrict__ out,
        GroupArgs g, int accumulate) {
    int flat = blockIdx.x;
    int wg = (flat & 7) * RZ_CHUNK + (flat >> 3);   // RZ_BLOCKS % 8 == 0
    int bx = wg % 7;
    int tq = wg / 7;
    int by = tq % 7;
    int bk = tq / 7;

    const int tid = threadIdx.x;
    const int tx = tid & 15;
    const int ty = tid >> 4;
    const int xo = bx * 32 + tx * 2;
    const int yo = by * 32 + ty * 2;

    float acc[2][2][3] = {};
    size_t ob0 = (((size_t)bk * OUT_HW + yo) * OUT_HW + xo) * 3;
    size_t ob1 = ob0 + OUT_HW * 3;
    if (accumulate) {
#pragma unroll
        for (int ch = 0; ch < 3; ++ch) {
            acc[0][0][ch] = out[ob0 + ch];
            acc[0][1][ch] = out[ob0 + 3 + ch];
            acc[1][0][ch] = out[ob1 + ch];
            acc[1][1][ch] = out[ob1 + 3 + ch];
        }
    }

    for (int c = 0; c < g.n; ++c) {
        const CfgEntry e = g.e[c];
        const float4* wrow = wtbl + e.tbl * (2 * OUT_HW);
        const int*    irow = itbl + e.tbl * (2 * OUT_HW);
        float4 wha = wrow[yo];
        float4 whb = wrow[yo + 1];
        float4 wwa = wrow[OUT_HW + xo];
        float4 wwb = wrow[OUT_HW + xo + 1];
        int i0a = irow[yo];
        int i0b = irow[yo + 1];
        int j0a = irow[OUT_HW + xo];
        int j0b = irow[OUT_HW + xo + 1];
        const uint2* plane = agg + (size_t)e.ws_off
                           + (size_t)bk * ((size_t)e.kh * e.kwp);

        switch ((e.mth << 2) | e.mtw) {
            case (2 << 2) | 2:
                taps4<3, 2>(plane, e.kh, e.kwp, i0a, i0b, j0a, j0b,
                            wha, whb, wwa, wwb, acc); break;
            case (3 << 2) | 2:
                taps4<5, 2>(plane, e.kh, e.kwp, i0a, i0b, j0a, j0b,
                            wha, whb, wwa, wwb, acc); break;
            case (2 << 2) | 3:
                taps4<3, 3>(plane, e.kh, e.kwp, i0a, i0b, j0a, j0b,
                            wha, whb, wwa, wwb, acc); break;
            case (3 << 2) | 3:
                taps4<5, 3>(plane, e.kh, e.kwp, i0a, i0b, j0a, j0b,
                            wha, whb, wwa, wwb, acc); break;
            case (4 << 2) | 3:
                taps4<6, 3>(plane, e.kh, e.kwp, i0a, i0b, j0a, j0b,
                            wha, whb, wwa, wwb, acc); break;
            case (3 << 2) | 4:
                taps4<5, 4>(plane, e.kh, e.kwp, i0a, i0b, j0a, j0b,
                            wha, whb, wwa, wwb, acc); break;
            default:
                taps4<6, 4>(plane, e.kh, e.kwp, i0a, i0b, j0a, j0b,
                            wha, whb, wwa, wwb, acc); break;
        }
    }

#pragma unroll
    for (int ch = 0; ch < 3; ++ch) {
        out[ob0 + ch]     = acc[0][0][ch];
        out[ob0 + 3 + ch] = acc[0][1][ch];
        out[ob1 + ch]     = acc[1][0][ch];
        out[ob1 + 3 + ch] = acc[1][1][ch];
    }
}

// ---------------------------------------------------------------------------
// Host launch
// ---------------------------------------------------------------------------
extern "C" void kernel_launch(void* const* d_in, const int* in_sizes, int n_in,
                              void* d_out, int out_size, void* d_ws, size_t ws_size,
                              hipStream_t stream) {
    const float* x   = (const float*)d_in[0];
    const float* wp3 = (const float*)d_in[1];
    const float* wp4 = (const float*)d_in[2];
    const float* wp5 = (const float*)d_in[3];
    float* out = (float*)d_out;
    float4* wtbl = (float4*)d_ws;
    int*    itbl = (int*)((char*)d_ws + WTBL_BYTES);
    float4* wT   = (float4*)((char*)d_ws + WT_OFF_BYTES);
    uint2*  agg  = (uint2*)((char*)d_ws + AGG_OFF_BYTES);

    // Build the 21 configs exactly as the reference does (double precision).
    struct { int stride, size, nscale; double scales[3]; int gh; } layers[3] = {
        {32, 48, 2, {pow(2.0, 1.0 / 3.0), pow(2.0, 2.0 / 3.0), 0.0}, 14},
        {64, 96, 2, {pow(2.0, 1.0 / 3.0), pow(2.0, 2.0 / 3.0), 0.0}, 7},
        {128, 192, 3, {1.0, pow(2.0, 1.0 / 3.0), pow(2.0, 2.0 / 3.0)}, 4},
    };
    const double ars[3] = {0.667, 1.0, 1.5};

    struct HostCfg {
        int kh, kw, kwp, stride, p0, p1, gh, gw, layer, anchor, mth, mtw, wt_off;
        int qpr, blocks_per_img;
    } cfg[NCFG];
    TablesArgs ta;
    TrArgs tr;
    int nc = 0, wt_run = 0;
    for (int L = 0; L < 3; ++L) {
        int anchor = 0;
        for (int si = 0; si < layers[L].nscale; ++si) {
            for (int ai = 0; ai < 3; ++ai) {
                double ss = (double)layers[L].size * layers[L].scales[si];
                double sq = pow(ars[ai], 0.5);
                int kh = (int)(ss / sq);
                int kw = (int)(ss * sq);
                HostCfg& e = cfg[nc];
                e.kh = kh; e.kw = kw;
                e.kwp = kw + (kw & 1);
                e.stride = layers[L].stride;
                e.p0 = (int)ceil((double)(kh - layers[L].stride) / 2.0);
                e.p1 = (int)ceil((double)(kw - layers[L].stride) / 2.0);
                e.gh = layers[L].gh; e.gw = layers[L].gh;
                e.layer = L; e.anchor = anchor++;
                e.mth = (kh < OUT_HW) ? 2 : (int)((2.0 * kh) / OUT_HW) + 1;
                e.mtw = (kw < OUT_HW) ? 2 : (int)((2.0 * kw) / OUT_HW) + 1;
                if (e.mth > 4) e.mth = 4;
                if (e.mtw > 4) e.mtw = 4;
                e.qpr = e.kwp / 2;
                e.blocks_per_img = (kh * e.qpr + 255) / 256;
                e.wt_off = wt_run;
                int gsz = e.gh * e.gw;
                wt_run += BATCH * gsz;
                ta.kh[nc] = kh; ta.kw[nc] = kw;
                tr.layer[nc] = L; tr.anchor[nc] = e.anchor;
                tr.gsz[nc] = gsz; tr.wt_off[nc] = e.wt_off;
                ++nc;
            }
        }
    }

    init_tables<<<NCFG * 2, 256, 0, stream>>>(wtbl, itbl, ta);
    transpose_w<<<dim3(NCFG, BATCH), 256, 0, stream>>>(wp3, wp4, wp5, wT, tr);

    size_t cap_px = (ws_size - AGG_OFF_BYTES) / 8;
    dim3 rgrid(RZ_BLOCKS);

    int i = 0;
    int first = 1;
    while (i < NCFG) {
        // build a group
        int gstart = i;
        size_t used = 0;
        while (i < NCFG) {
            size_t need = (size_t)cfg[i].kh * cfg[i].kwp * (BATCH * KK);
            if (i > gstart && used + need > cap_px) break;
            used += need;
            ++i;
            if (used >= cap_px) break;
        }
        GroupArgs g; g.n = 0;
        AggArgs aa; aa.n = 0;
        int ablocks = 0;
        size_t off = 0;
        for (int c = gstart; c < i; ++c) {
            ACfg& lc = aa.e[aa.n++];
            lc.kh = cfg[c].kh; lc.kw = cfg[c].kw; lc.kwp = cfg[c].kwp;
            lc.p0 = cfg[c].p0; lc.p1 = cfg[c].p1;
            lc.layer = cfg[c].layer;
            lc.qpr = cfg[c].qpr;
            lc.wt_off = cfg[c].wt_off;
            lc.ws_off = (int)off;
            lc.block_start = ablocks;
            lc.blocks_per_img = cfg[c].blocks_per_img;
            ablocks += cfg[c].blocks_per_img * BATCH;
            CfgEntry& re = g.e[g.n++];
            re.kh = cfg[c].kh; re.kw = cfg[c].kw; re.kwp = cfg[c].kwp;
            re.mth = cfg[c].mth; re.mtw = cfg[c].mtw;
            re.tbl = c; re.ws_off = (int)off;
            off += (size_t)cfg[c].kh * cfg[c].kwp * (BATCH * KK);
        }
        agg_all<<<ablocks, 256, 0, stream>>>(x, wT, agg, aa);
        resize_kernel<<<rgrid, 256, 0, stream>>>(agg, wtbl, itbl, out, g, first ? 0 : 1);
        first = 0;
    }
    (void)in_sizes; (void)n_in; (void)out_size;
}

// Round 3
// 280.668 us; speedup vs baseline: 1.1965x; 1.1965x over previous
//
#include <hip/hip_runtime.h>
#include <math.h>

// ---------------------------------------------------------------------------
// AttentionNet weighted-anchor aggregator.
//   x:  (8, 448, 448, 3) f32
//   wp3:(8, 6, 4, 14, 14) f32   wp4:(8, 6, 4, 7, 7) f32   wp5:(8, 9, 4, 4, 4) f32
//   out:(32, 224, 224, 3) f32 = sum over 21 configs of
//        resize_bilinear( einsum('bkij,bihjwc->bkhwc', w, patches), 224,224 )
//
// Phase 0a: init_tables — normalized zero-padded 4-tap weights + i0.
// Phase 0b: transpose_w — weights to [cfg][b][grid][k0..k3] float4.
// Phase A : agg_all — branch-free inner loop; the two px of a pair are packed
//           into float2 ext-vectors so the 24 FMAs become 12 v_pk_fma_f32
//           (gfx950 packed f32 = 2x scalar rate). Unsigned-min address clamp.
//           Image-per-XCD decomposition (b = local & 7). kwp-padded rows,
//           one aligned uint4 (2 px bf16x3) store per k.
// Phase B : resize_kernel — per-px direct gather (round-1 structure: lowest
//           VGPR, all tap loads issued up-front), tables in LDS (1 barrier).
// GROUPS  : configs are processed in ~<=9.2M-px groups (agg <= ~70 MB), each
//           group = agg dispatch + resize dispatch (accumulating into out).
//           Keeps each group's agg L3-resident for the resize gathers —
//           the r1/r2 resize was HBM-latency-bound (FETCH 92MB, 900cy taps)
//           because 180MB agg + 339MB x churned the 256MB L3.
// ---------------------------------------------------------------------------

#define BATCH 8
#define KK 4
#define OUT_HW 224
#define IMG_HW 448
#define NCFG 21

#define WTBL_BYTES (NCFG * 2 * OUT_HW * 16)     // 150528
#define ITBL_BYTES (NCFG * 2 * OUT_HW * 4)      // 37632
#define WT_OFF_BYTES (WTBL_BYTES + ITBL_BYTES)  // 188160
#define WT_F4 12912                             // 8 * (6*196 + 6*49 + 9*16)
#define AGG_OFF_BYTES (WT_OFF_BYTES + WT_F4 * 16)  // 394752 (16B aligned)

#define GROUP_PX_CAP 9200000                    // ~70 MB agg per group

typedef float v2f __attribute__((ext_vector_type(2)));

struct CfgEntry {          // resize view of a config
    int kh, kw, kwp;
    int mth, mtw;          // max tap count per dim (2..4)
    int tbl;               // global cfg index (table lookup)
    int ws_off;            // px (uint2) offset in agg region
};

struct GroupArgs {
    CfgEntry e[NCFG];
    int n;
};

struct ACfg {              // agg view of a config
    int kh, kw, kwp, p0, p1;
    int layer;             // 0=p3, 1=p4, 2=p5
    int qpr;               // pairs (2px) per row = kwp/2
    int wt_off;            // float4 offset of transposed weights
    int ws_off;            // px offset in agg region
    int block_start;
    int blocks_per_img;    // ceil(kh*qpr/256)
};

struct AggArgs {
    ACfg e[NCFG];
    int n;
};

struct TablesArgs { int kh[NCFG]; int kw[NCFG]; };

struct TrArgs {
    int layer[NCFG];
    int anchor[NCFG];
    int gsz[NCFG];
    int wt_off[NCFG];
};

struct F3 { float a, b, c; };

__device__ inline unsigned int bf16_rne(float f) {
    unsigned int u = __float_as_uint(f);
    return (u + 0x7fffu + ((u >> 16) & 1u)) >> 16;
}

// ---------------------------------------------------------------------------
// Phase 0a: tap tables. jax.image.resize('bilinear', antialias=True):
//   inv=in/out; ks=max(inv,1); sf=(o+0.5)*inv-0.5; taps i in
//   [ceil(sf-ks), floor(sf+ks)] clamped, w=max(0,1-|i-sf|/ks) normalized.
// ---------------------------------------------------------------------------
__global__ __launch_bounds__(256) void init_tables(float4* __restrict__ wtbl,
                                                   int* __restrict__ itbl,
                                                   TablesArgs t) {
    int cfg = blockIdx.x >> 1;
    int dim = blockIdx.x & 1;
    int o = threadIdx.x;
    if (o >= OUT_HW) return;
    int n = dim ? t.kw[cfg] : t.kh[cfg];

    float inv = (float)(1.0 / ((double)OUT_HW / (double)n));
    float ks  = inv > 1.f ? inv : 1.f;
    float rks = 1.f / ks;
    float sf  = ((float)o + 0.5f) * inv - 0.5f;
    int i0 = (int)ceilf(sf - ks);  if (i0 < 0) i0 = 0;
    int i1 = (int)floorf(sf + ks); if (i1 > n - 1) i1 = n - 1;
    float sum = 0.f;
    for (int i = i0; i <= i1; ++i) {
        float v = 1.f - fabsf((float)i - sf) * rks;
        sum += (v > 0.f ? v : 0.f);
    }
    float rsum = 1.f / sum;
    float w[4];
#pragma unroll
    for (int d = 0; d < 4; ++d) {
        int i = i0 + d;
        float v = 0.f;
        if (i <= i1) {
            v = 1.f - fabsf((float)i - sf) * rks;
            v = (v > 0.f ? v : 0.f) * rsum;
        }
        w[d] = v;
    }
    int idx = cfg * (2 * OUT_HW) + dim * OUT_HW + o;
    wtbl[idx] = make_float4(w[0], w[1], w[2], w[3]);
    itbl[idx] = i0;
}

// ---------------------------------------------------------------------------
// Phase 0b: transpose weights (B,A,K,gh,gw) -> per cfg [b][g][k0..k3] float4.
// ---------------------------------------------------------------------------
__global__ __launch_bounds__(256) void transpose_w(
        const float* __restrict__ wp3, const float* __restrict__ wp4,
        const float* __restrict__ wp5, float4* __restrict__ wT, TrArgs t) {
    int cfg = blockIdx.x;
    int b = blockIdx.y;
    int gsz = t.gsz[cfg];
    const float* base;
    int A;
    if (t.layer[cfg] == 0)      { base = wp3; A = 6; }
    else if (t.layer[cfg] == 1) { base = wp4; A = 6; }
    else                        { base = wp5; A = 9; }
    const float* src = base + (size_t)(b * A + t.anchor[cfg]) * (KK * gsz);
    for (int g = threadIdx.x; g < gsz; g += 256) {
        wT[t.wt_off[cfg] + b * gsz + g] =
            make_float4(src[0 * gsz + g], src[1 * gsz + g],
                        src[2 * gsz + g], src[3 * gsz + g]);
    }
}

// ---------------------------------------------------------------------------
// Agg body (templated): 2 consecutive px per thread packed as float2 lanes;
// 12 v_pk_fma_f32 per (i,j) instead of 24 scalar FMA. Branch-free: clamped
// (v_min_u32) dwordx3 loads always issue; invalid px zeroed by cndmask.
// ---------------------------------------------------------------------------
template <int GH, int GW, int STRIDE>
__device__ inline void agg_body(const ACfg& c, int b, int h, int w0,
                                const float* __restrict__ xb,
                                const float4* __restrict__ wlds,
                                uint2* __restrict__ agg) {
    v2f acc2[4][3];
#pragma unroll
    for (int k = 0; k < 4; ++k)
#pragma unroll
        for (int ch = 0; ch < 3; ++ch) { acc2[k][ch].x = 0.f; acc2[k][ch].y = 0.f; }

    const int rb = h - c.p0;
    // valid i range: 0 <= rb + i*STRIDE <= IMG_HW-1
    int ilo = rb >= 0 ? 0 : (-rb + STRIDE - 1) / STRIDE;
    int ihi = (IMG_HW - 1 - rb) / STRIDE;
    if (ihi > GH - 1) ihi = GH - 1;

    const int cb = w0 - c.p1;

#pragma unroll 1
    for (int i = ilo; i <= ihi; ++i) {
        const float* xr = xb + (size_t)(rb + i * STRIDE) * (IMG_HW * 3);
        const float4* wrow = wlds + i * GW;
#pragma unroll
        for (int j = 0; j < GW; ++j) {
            int col = cb + j * STRIDE;
            unsigned cc0 = (unsigned)col;
            if (cc0 > (unsigned)(IMG_HW - 1)) cc0 = (unsigned)(IMG_HW - 1); // v_min_u32
            unsigned cc1 = (unsigned)(col + 1);
            if (cc1 > (unsigned)(IMG_HW - 1)) cc1 = (unsigned)(IMG_HW - 1);
            F3 v0 = *(const F3*)(xr + (size_t)cc0 * 3);
            F3 v1 = *(const F3*)(xr + (size_t)cc1 * 3);
            bool k0 = (unsigned)col < (unsigned)IMG_HW;
            bool k1 = (unsigned)(col + 1) < (unsigned)IMG_HW;
            v2f d0, d1, d2;
            d0.x = k0 ? v0.a : 0.f;  d0.y = k1 ? v1.a : 0.f;
            d1.x = k0 ? v0.b : 0.f;  d1.y = k1 ? v1.b : 0.f;
            d2.x = k0 ? v0.c : 0.f;  d2.y = k1 ? v1.c : 0.f;
            float4 wk = wrow[j];   // uniform address -> broadcast b128
            v2f wv0 = {wk.x, wk.x};
            v2f wv1 = {wk.y, wk.y};
            v2f wv2 = {wk.z, wk.z};
            v2f wv3 = {wk.w, wk.w};
            acc2[0][0] = __builtin_elementwise_fma(wv0, d0, acc2[0][0]);
            acc2[0][1] = __builtin_elementwise_fma(wv0, d1, acc2[0][1]);
            acc2[0][2] = __builtin_elementwise_fma(wv0, d2, acc2[0][2]);
            acc2[1][0] = __builtin_elementwise_fma(wv1, d0, acc2[1][0]);
            acc2[1][1] = __builtin_elementwise_fma(wv1, d1, acc2[1][1]);
            acc2[1][2] = __builtin_elementwise_fma(wv1, d2, acc2[1][2]);
            acc2[2][0] = __builtin_elementwise_fma(wv2, d0, acc2[2][0]);
            acc2[2][1] = __builtin_elementwise_fma(wv2, d1, acc2[2][1]);
            acc2[2][2] = __builtin_elementwise_fma(wv2, d2, acc2[2][2]);
            acc2[3][0] = __builtin_elementwise_fma(wv3, d0, acc2[3][0]);
            acc2[3][1] = __builtin_elementwise_fma(wv3, d1, acc2[3][1]);
            acc2[3][2] = __builtin_elementwise_fma(wv3, d2, acc2[3][2]);
        }
    }

    const int npix = c.kh * c.kwp;
#pragma unroll
    for (int k = 0; k < 4; ++k) {
        size_t base = (size_t)c.ws_off + (size_t)(b * KK + k) * npix
                    + (size_t)h * c.kwp + w0;
        uint4 o;
        o.x = bf16_rne(acc2[k][0].x) | (bf16_rne(acc2[k][1].x) << 16);
        o.y = bf16_rne(acc2[k][2].x);
        o.z = bf16_rne(acc2[k][0].y) | (bf16_rne(acc2[k][1].y) << 16);
        o.w = bf16_rne(acc2[k][2].y);
        *(uint4*)(agg + base) = o;   // base even -> 16B aligned
    }
}

// ---------------------------------------------------------------------------
// Phase A: one dispatch per group; block-uniform layer switch.
// b = local & 7: with round-robin block->XCD dispatch and 8 images == 8 XCDs,
// each XCD only ever touches one image (block_start is always 8-aligned).
// ---------------------------------------------------------------------------
__global__ __launch_bounds__(256, 4) void agg_all(
        const float* __restrict__ x,
        const float4* __restrict__ wT,
        uint2* __restrict__ agg,
        AggArgs a) {
    int bid = blockIdx.x;
    int ci = 0;
    while (ci + 1 < a.n && bid >= a.e[ci + 1].block_start) ci++;
    const ACfg c = a.e[ci];
    int local = bid - c.block_start;
    int b     = local & 7;           // image-per-XCD
    int sblk  = local >> 3;

    const int gsz = (c.layer == 0) ? 196 : (c.layer == 1) ? 49 : 16;
    __shared__ float4 wlds[196];
    for (int t = threadIdx.x; t < gsz; t += 256)
        wlds[t] = wT[c.wt_off + b * gsz + t];
    __syncthreads();

    int pidx = sblk * 256 + (int)threadIdx.x;
    if (pidx >= c.kh * c.qpr) return;
    int h  = pidx / c.qpr;
    int w0 = (pidx - h * c.qpr) * 2;

    const float* __restrict__ xb = x + (size_t)b * (IMG_HW * IMG_HW * 3);
    if (c.layer == 0)      agg_body<14, 14, 32>(c, b, h, w0, xb, wlds, agg);
    else if (c.layer == 1) agg_body<7, 7, 64>(c, b, h, w0, xb, wlds, agg);
    else                   agg_body<4, 4, 128>(c, b, h, w0, xb, wlds, agg);
}

// ---------------------------------------------------------------------------
// Tap micro-kernel: TH x TW taps gathered directly from global agg (bf16x3
// uint2 px, kwp-padded rows). All loads issued up-front for max MLP.
// Out-of-range taps carry weight 0 in the tables; addresses are clamped.
// ---------------------------------------------------------------------------
template <int TH, int TW>
__device__ inline void taps_direct(const uint2* __restrict__ base,
                                   int kh, int kw, int kwp, int i0, int j0,
                                   float4 wh4, float4 ww4,
                                   float& a0, float& a1, float& a2) {
    const float* wh = (const float*)&wh4;
    const float* ww = (const float*)&ww4;
    uint2 v[TH][TW];
#pragma unroll
    for (int d = 0; d < TH; ++d) {
        int gi = i0 + d;
        if (gi > kh - 1) gi = kh - 1;
        const uint2* rp = base + (size_t)gi * kwp;
#pragma unroll
        for (int e = 0; e < TW; ++e) {
            int gj = j0 + e;
            if (gj > kw - 1) gj = kw - 1;
            v[d][e] = rp[gj];
        }
    }
#pragma unroll
    for (int d = 0; d < TH; ++d) {
        float r0 = 0.f, r1 = 0.f, r2 = 0.f;
#pragma unroll
        for (int e = 0; e < TW; ++e) {
            uint2 t = v[d][e];
            float c0 = __uint_as_float(t.x << 16);
            float c1 = __uint_as_float(t.x & 0xffff0000u);
            float c2 = __uint_as_float(t.y << 16);
            float w = ww[e];
            r0 = fmaf(w, c0, r0);
            r1 = fmaf(w, c1, r1);
            r2 = fmaf(w, c2, r2);
        }
        a0 = fmaf(wh[d], r0, a0);
        a1 = fmaf(wh[d], r1, a1);
        a2 = fmaf(wh[d], r2, a2);
    }
}

// ---------------------------------------------------------------------------
// Phase B: barrier-free resize (one barrier for LDS table staging).
// One output px per thread, z = bk (32). Tap data gathered directly from
// global agg — L3-hot because groups are capped at ~70 MB.
// ---------------------------------------------------------------------------
__global__ __launch_bounds__(256) void resize_kernel(
        const uint2* __restrict__ agg,
        const float4* __restrict__ wtbl,
        const int* __restrict__ itbl,
        float* __restrict__ out,
        GroupArgs g, int accumulate) {
    const int tid = threadIdx.x;
    const int tx = tid & 15;
    const int ty = tid >> 4;
    const int xo = blockIdx.x * 16 + tx;
    const int yo = blockIdx.y * 16 + ty;
    const int bk = blockIdx.z;

    __shared__ float4 wlds[NCFG * 32];
    __shared__ int    ilds[NCFG * 32];

    const int nent = g.n * 32;
    for (int e = tid; e < nent; e += 256) {
        int ci  = e >> 5;
        int r   = e & 31;
        int isW = r >> 4;
        int idx = r & 15;
        int base_o = isW ? (blockIdx.x * 16) : (blockIdx.y * 16);
        int src = g.e[ci].tbl * (2 * OUT_HW) + isW * OUT_HW + base_o + idx;
        wlds[ci * 32 + r] = wtbl[src];
        ilds[ci * 32 + r] = itbl[src];
    }
    __syncthreads();

    size_t ob = (((size_t)bk * OUT_HW + yo) * OUT_HW + xo) * 3;
    float a0, a1, a2;
    if (accumulate) {
        a0 = out[ob]; a1 = out[ob + 1]; a2 = out[ob + 2];
    } else {
        a0 = a1 = a2 = 0.f;
    }

    for (int c = 0; c < g.n; ++c) {
        const CfgEntry e = g.e[c];
        float4 wh4 = wlds[c * 32 + ty];
        float4 ww4 = wlds[c * 32 + 16 + tx];
        int i0 = ilds[c * 32 + ty];
        int j0 = ilds[c * 32 + 16 + tx];
        const uint2* base = agg + (size_t)e.ws_off
                          + (size_t)bk * ((size_t)e.kh * e.kwp);

        switch ((e.mth << 2) | e.mtw) {
            case (2 << 2) | 2:
                taps_direct<2, 2>(base, e.kh, e.kw, e.kwp, i0, j0, wh4, ww4, a0, a1, a2);
                break;
            case (3 << 2) | 2:
                taps_direct<3, 2>(base, e.kh, e.kw, e.kwp, i0, j0, wh4, ww4, a0, a1, a2);
                break;
            case (2 << 2) | 3:
                taps_direct<2, 3>(base, e.kh, e.kw, e.kwp, i0, j0, wh4, ww4, a0, a1, a2);
                break;
            case (3 << 2) | 3:
                taps_direct<3, 3>(base, e.kh, e.kw, e.kwp, i0, j0, wh4, ww4, a0, a1, a2);
                break;
            case (4 << 2) | 3:
                taps_direct<4, 3>(base, e.kh, e.kw, e.kwp, i0, j0, wh4, ww4, a0, a1, a2);
                break;
            case (3 << 2) | 4:
                taps_direct<3, 4>(base, e.kh, e.kw, e.kwp, i0, j0, wh4, ww4, a0, a1, a2);
                break;
            default:
                taps_direct<4, 4>(base, e.kh, e.kw, e.kwp, i0, j0, wh4, ww4, a0, a1, a2);
                break;
        }
    }

    out[ob + 0] = a0; out[ob + 1] = a1; out[ob + 2] = a2;
}

// ---------------------------------------------------------------------------
// Host launch
// ---------------------------------------------------------------------------
extern "C" void kernel_launch(void* const* d_in, const int* in_sizes, int n_in,
                              void* d_out, int out_size, void* d_ws, size_t ws_size,
                              hipStream_t stream) {
    const float* x   = (const float*)d_in[0];
    const float* wp3 = (const float*)d_in[1];
    const float* wp4 = (const float*)d_in[2];
    const float* wp5 = (const float*)d_in[3];
    float* out = (float*)d_out;
    float4* wtbl = (float4*)d_ws;
    int*    itbl = (int*)((char*)d_ws + WTBL_BYTES);
    float4* wT   = (float4*)((char*)d_ws + WT_OFF_BYTES);
    uint2*  agg  = (uint2*)((char*)d_ws + AGG_OFF_BYTES);

    // Build the 21 configs exactly as the reference does (double precision).
    struct { int stride, size, nscale; double scales[3]; int gh; } layers[3] = {
        {32, 48, 2, {pow(2.0, 1.0 / 3.0), pow(2.0, 2.0 / 3.0), 0.0}, 14},
        {64, 96, 2, {pow(2.0, 1.0 / 3.0), pow(2.0, 2.0 / 3.0), 0.0}, 7},
        {128, 192, 3, {1.0, pow(2.0, 1.0 / 3.0), pow(2.0, 2.0 / 3.0)}, 4},
    };
    const double ars[3] = {0.667, 1.0, 1.5};

    struct HostCfg {
        int kh, kw, kwp, stride, p0, p1, gh, gw, layer, anchor, mth, mtw, wt_off;
        int qpr, blocks_per_img;
    } cfg[NCFG];
    TablesArgs ta;
    TrArgs tr;
    int nc = 0, wt_run = 0;
    for (int L = 0; L < 3; ++L) {
        int anchor = 0;
        for (int si = 0; si < layers[L].nscale; ++si) {
            for (int ai = 0; ai < 3; ++ai) {
                double ss = (double)layers[L].size * layers[L].scales[si];
                double sq = pow(ars[ai], 0.5);
                int kh = (int)(ss / sq);
                int kw = (int)(ss * sq);
                HostCfg& e = cfg[nc];
                e.kh = kh; e.kw = kw;
                e.kwp = kw + (kw & 1);
                e.stride = layers[L].stride;
                e.p0 = (int)ceil((double)(kh - layers[L].stride) / 2.0);
                e.p1 = (int)ceil((double)(kw - layers[L].stride) / 2.0);
                e.gh = layers[L].gh; e.gw = layers[L].gh;
                e.layer = L; e.anchor = anchor++;
                e.mth = (kh < OUT_HW) ? 2 : (int)((2.0 * kh) / OUT_HW) + 1;
                e.mtw = (kw < OUT_HW) ? 2 : (int)((2.0 * kw) / OUT_HW) + 1;
                if (e.mth > 4) e.mth = 4;
                if (e.mtw > 4) e.mtw = 4;
                e.qpr = e.kwp / 2;
                e.blocks_per_img = (kh * e.qpr + 255) / 256;
                e.wt_off = wt_run;
                int gsz = e.gh * e.gw;
                wt_run += BATCH * gsz;
                ta.kh[nc] = kh; ta.kw[nc] = kw;
                tr.layer[nc] = L; tr.anchor[nc] = e.anchor;
                tr.gsz[nc] = gsz; tr.wt_off[nc] = e.wt_off;
                ++nc;
            }
        }
    }

    init_tables<<<NCFG * 2, 256, 0, stream>>>(wtbl, itbl, ta);
    transpose_w<<<dim3(NCFG, BATCH), 256, 0, stream>>>(wp3, wp4, wp5, wT, tr);

    size_t cap_px = (ws_size - AGG_OFF_BYTES) / 8;
    if (cap_px > (size_t)GROUP_PX_CAP) cap_px = (size_t)GROUP_PX_CAP;
    dim3 rgrid(OUT_HW / 16, OUT_HW / 16, BATCH * KK);

    int i = 0;
    int first = 1;
    while (i < NCFG) {
        // build a group
        int gstart = i;
        size_t used = 0;
        while (i < NCFG) {
            size_t need = (size_t)cfg[i].kh * cfg[i].kwp * (BATCH * KK);
            if (i > gstart && used + need > cap_px) break;
            used += need;
            ++i;
            if (used >= cap_px) break;
        }
        GroupArgs g; g.n = 0;
        AggArgs aa; aa.n = 0;
        int ablocks = 0;
        size_t off = 0;
        for (int c = gstart; c < i; ++c) {
            ACfg& lc = aa.e[aa.n++];
            lc.kh = cfg[c].kh; lc.kw = cfg[c].kw; lc.kwp = cfg[c].kwp;
            lc.p0 = cfg[c].p0; lc.p1 = cfg[c].p1;
            lc.layer = cfg[c].layer;
            lc.qpr = cfg[c].qpr;
            lc.wt_off = cfg[c].wt_off;
            lc.ws_off = (int)off;
            lc.block_start = ablocks;
            lc.blocks_per_img = cfg[c].blocks_per_img;
            ablocks += cfg[c].blocks_per_img * BATCH;
            CfgEntry& re = g.e[g.n++];
            re.kh = cfg[c].kh; re.kw = cfg[c].kw; re.kwp = cfg[c].kwp;
            re.mth = cfg[c].mth; re.mtw = cfg[c].mtw;
            re.tbl = c; re.ws_off = (int)off;
            off += (size_t)cfg[c].kh * cfg[c].kwp * (BATCH * KK);
        }
        agg_all<<<ablocks, 256, 0, stream>>>(x, wT, agg, aa);
        resize_kernel<<<rgrid, 256, 0, stream>>>(agg, wtbl, itbl, out, g, first ? 0 : 1);
        first = 0;
    }
    (void)in_sizes; (void)n_in; (void)out_size;
}

// Round 4
// 275.476 us; speedup vs baseline: 1.2191x; 1.0188x over previous
//
#include <hip/hip_runtime.h>
#include <math.h>

// ---------------------------------------------------------------------------
// AttentionNet weighted-anchor aggregator.
//   x:  (8, 448, 448, 3) f32
//   wp3:(8, 6, 4, 14, 14) f32   wp4:(8, 6, 4, 7, 7) f32   wp5:(8, 9, 4, 4, 4) f32
//   out:(32, 224, 224, 3) f32 = sum over 21 configs of
//        resize_bilinear( einsum('bkij,bihjwc->bkhwc', w, patches), 224,224 )
//
// Phase 0a: init_tables — normalized zero-padded 4-tap weights + i0.
// Phase 0b: transpose_w — weights to [cfg][b][grid][k0..k3] float4.
// Phase A : agg_all — branch-free inner loop, float2-packed (v_pk_fma_f32),
//           image-per-XCD decomposition, kwp-padded rows, uint4 stores.
// Phase B : resize_static<CSTART,CEND> — FULLY COMPILE-TIME cfg rounds.
//           The 21 cfg geometries and the 3-group split are static, so the
//           per-cfg switch is replaced by if-constexpr recursion with
//           constexpr (kh,kw,kwp,mth,mtw,ws_off). No runtime switch =>
//           the compiler pipelines tap loads ACROSS rounds (the r3 resize
//           was bound by 21 serial latency-chained rounds, ~160us vs ~29us
//           VALU floor).
// GROUPS  : static {0..14}, {15..18}, {19..20} (same split r3 chose
//           dynamically): agg groups stay <=65MB => L3/L2-resident taps.
// ---------------------------------------------------------------------------

#define BATCH 8
#define KK 4
#define OUT_HW 224
#define IMG_HW 448
#define NCFG 21

#define WTBL_BYTES (NCFG * 2 * OUT_HW * 16)     // 150528
#define ITBL_BYTES (NCFG * 2 * OUT_HW * 4)      // 37632
#define WT_OFF_BYTES (WTBL_BYTES + ITBL_BYTES)  // 188160
#define WT_F4 12912                             // 8 * (6*196 + 6*49 + 9*16)
#define AGG_OFF_BYTES (WT_OFF_BYTES + WT_F4 * 16)  // 394752 (16B aligned)

typedef float v2f __attribute__((ext_vector_type(2)));

// Compile-time cfg geometry (== host double-precision construction; margins
// to int-truncation boundaries are >=0.05 so this is exact).
static constexpr int cKH[NCFG]  = {74,60,49,93,76,62, 148,120,98,186,152,124,
                                   235,192,156,296,241,197,373,304,248};
static constexpr int cKW[NCFG]  = {49,60,74,62,76,93, 98,120,148,124,152,186,
                                   156,192,235,197,241,296,248,304,373};
static constexpr int cMTH[NCFG] = {2,2,2,2,2,2, 2,2,2,2,2,2, 3,2,2,3,3,2,4,3,3};
static constexpr int cMTW[NCFG] = {2,2,2,2,2,2, 2,2,2,2,2,2, 2,2,3,2,3,3,3,3,4};

__host__ __device__ constexpr int ckwp(int c) { return cKW[c] + (cKW[c] & 1); }
__host__ __device__ constexpr long cwsoff(int c, int g) {
    long o = 0;
    for (int k = g; k < c; ++k) o += (long)cKH[k] * ckwp(k) * (BATCH * KK);
    return o;
}

struct ACfg {              // agg view of a config
    int kh, kw, kwp, p0, p1;
    int layer;             // 0=p3, 1=p4, 2=p5
    int qpr;               // pairs (2px) per row = kwp/2
    int wt_off;            // float4 offset of transposed weights
    int ws_off;            // px offset in agg region
    int block_start;
    int blocks_per_img;    // ceil(kh*qpr/256)
};

struct AggArgs {
    ACfg e[NCFG];
    int n;
};

struct TablesArgs { int kh[NCFG]; int kw[NCFG]; };

struct TrArgs {
    int layer[NCFG];
    int anchor[NCFG];
    int gsz[NCFG];
    int wt_off[NCFG];
};

struct F3 { float a, b, c; };

__device__ inline unsigned int bf16_rne(float f) {
    unsigned int u = __float_as_uint(f);
    return (u + 0x7fffu + ((u >> 16) & 1u)) >> 16;
}

// ---------------------------------------------------------------------------
// Phase 0a: tap tables. jax.image.resize('bilinear', antialias=True):
//   inv=in/out; ks=max(inv,1); sf=(o+0.5)*inv-0.5; taps i in
//   [ceil(sf-ks), floor(sf+ks)] clamped, w=max(0,1-|i-sf|/ks) normalized.
// ---------------------------------------------------------------------------
__global__ __launch_bounds__(256) void init_tables(float4* __restrict__ wtbl,
                                                   int* __restrict__ itbl,
                                                   TablesArgs t) {
    int cfg = blockIdx.x >> 1;
    int dim = blockIdx.x & 1;
    int o = threadIdx.x;
    if (o >= OUT_HW) return;
    int n = dim ? t.kw[cfg] : t.kh[cfg];

    float inv = (float)(1.0 / ((double)OUT_HW / (double)n));
    float ks  = inv > 1.f ? inv : 1.f;
    float rks = 1.f / ks;
    float sf  = ((float)o + 0.5f) * inv - 0.5f;
    int i0 = (int)ceilf(sf - ks);  if (i0 < 0) i0 = 0;
    int i1 = (int)floorf(sf + ks); if (i1 > n - 1) i1 = n - 1;
    float sum = 0.f;
    for (int i = i0; i <= i1; ++i) {
        float v = 1.f - fabsf((float)i - sf) * rks;
        sum += (v > 0.f ? v : 0.f);
    }
    float rsum = 1.f / sum;
    float w[4];
#pragma unroll
    for (int d = 0; d < 4; ++d) {
        int i = i0 + d;
        float v = 0.f;
        if (i <= i1) {
            v = 1.f - fabsf((float)i - sf) * rks;
            v = (v > 0.f ? v : 0.f) * rsum;
        }
        w[d] = v;
    }
    int idx = cfg * (2 * OUT_HW) + dim * OUT_HW + o;
    wtbl[idx] = make_float4(w[0], w[1], w[2], w[3]);
    itbl[idx] = i0;
}

// ---------------------------------------------------------------------------
// Phase 0b: transpose weights (B,A,K,gh,gw) -> per cfg [b][g][k0..k3] float4.
// ---------------------------------------------------------------------------
__global__ __launch_bounds__(256) void transpose_w(
        const float* __restrict__ wp3, const float* __restrict__ wp4,
        const float* __restrict__ wp5, float4* __restrict__ wT, TrArgs t) {
    int cfg = blockIdx.x;
    int b = blockIdx.y;
    int gsz = t.gsz[cfg];
    const float* base;
    int A;
    if (t.layer[cfg] == 0)      { base = wp3; A = 6; }
    else if (t.layer[cfg] == 1) { base = wp4; A = 6; }
    else                        { base = wp5; A = 9; }
    const float* src = base + (size_t)(b * A + t.anchor[cfg]) * (KK * gsz);
    for (int g = threadIdx.x; g < gsz; g += 256) {
        wT[t.wt_off[cfg] + b * gsz + g] =
            make_float4(src[0 * gsz + g], src[1 * gsz + g],
                        src[2 * gsz + g], src[3 * gsz + g]);
    }
}

// ---------------------------------------------------------------------------
// Agg body (templated): 2 consecutive px per thread packed as float2 lanes;
// 12 v_pk_fma_f32 per (i,j) instead of 24 scalar FMA. Branch-free: clamped
// (v_min_u32) dwordx3 loads always issue; invalid px zeroed by cndmask.
// ---------------------------------------------------------------------------
template <int GH, int GW, int STRIDE>
__device__ inline void agg_body(const ACfg& c, int b, int h, int w0,
                                const float* __restrict__ xb,
                                const float4* __restrict__ wlds,
                                uint2* __restrict__ agg) {
    v2f acc2[4][3];
#pragma unroll
    for (int k = 0; k < 4; ++k)
#pragma unroll
        for (int ch = 0; ch < 3; ++ch) { acc2[k][ch].x = 0.f; acc2[k][ch].y = 0.f; }

    const int rb = h - c.p0;
    // valid i range: 0 <= rb + i*STRIDE <= IMG_HW-1
    int ilo = rb >= 0 ? 0 : (-rb + STRIDE - 1) / STRIDE;
    int ihi = (IMG_HW - 1 - rb) / STRIDE;
    if (ihi > GH - 1) ihi = GH - 1;

    const int cb = w0 - c.p1;

#pragma unroll 1
    for (int i = ilo; i <= ihi; ++i) {
        const float* xr = xb + (size_t)(rb + i * STRIDE) * (IMG_HW * 3);
        const float4* wrow = wlds + i * GW;
#pragma unroll
        for (int j = 0; j < GW; ++j) {
            int col = cb + j * STRIDE;
            unsigned cc0 = (unsigned)col;
            if (cc0 > (unsigned)(IMG_HW - 1)) cc0 = (unsigned)(IMG_HW - 1); // v_min_u32
            unsigned cc1 = (unsigned)(col + 1);
            if (cc1 > (unsigned)(IMG_HW - 1)) cc1 = (unsigned)(IMG_HW - 1);
            F3 v0 = *(const F3*)(xr + (size_t)cc0 * 3);
            F3 v1 = *(const F3*)(xr + (size_t)cc1 * 3);
            bool k0 = (unsigned)col < (unsigned)IMG_HW;
            bool k1 = (unsigned)(col + 1) < (unsigned)IMG_HW;
            v2f d0, d1, d2;
            d0.x = k0 ? v0.a : 0.f;  d0.y = k1 ? v1.a : 0.f;
            d1.x = k0 ? v0.b : 0.f;  d1.y = k1 ? v1.b : 0.f;
            d2.x = k0 ? v0.c : 0.f;  d2.y = k1 ? v1.c : 0.f;
            float4 wk = wrow[j];   // uniform address -> broadcast b128
            v2f wv0 = {wk.x, wk.x};
            v2f wv1 = {wk.y, wk.y};
            v2f wv2 = {wk.z, wk.z};
            v2f wv3 = {wk.w, wk.w};
            acc2[0][0] = __builtin_elementwise_fma(wv0, d0, acc2[0][0]);
            acc2[0][1] = __builtin_elementwise_fma(wv0, d1, acc2[0][1]);
            acc2[0][2] = __builtin_elementwise_fma(wv0, d2, acc2[0][2]);
            acc2[1][0] = __builtin_elementwise_fma(wv1, d0, acc2[1][0]);
            acc2[1][1] = __builtin_elementwise_fma(wv1, d1, acc2[1][1]);
            acc2[1][2] = __builtin_elementwise_fma(wv1, d2, acc2[1][2]);
            acc2[2][0] = __builtin_elementwise_fma(wv2, d0, acc2[2][0]);
            acc2[2][1] = __builtin_elementwise_fma(wv2, d1, acc2[2][1]);
            acc2[2][2] = __builtin_elementwise_fma(wv2, d2, acc2[2][2]);
            acc2[3][0] = __builtin_elementwise_fma(wv3, d0, acc2[3][0]);
            acc2[3][1] = __builtin_elementwise_fma(wv3, d1, acc2[3][1]);
            acc2[3][2] = __builtin_elementwise_fma(wv3, d2, acc2[3][2]);
        }
    }

    const int npix = c.kh * c.kwp;
#pragma unroll
    for (int k = 0; k < 4; ++k) {
        size_t base = (size_t)c.ws_off + (size_t)(b * KK + k) * npix
                    + (size_t)h * c.kwp + w0;
        uint4 o;
        o.x = bf16_rne(acc2[k][0].x) | (bf16_rne(acc2[k][1].x) << 16);
        o.y = bf16_rne(acc2[k][2].x);
        o.z = bf16_rne(acc2[k][0].y) | (bf16_rne(acc2[k][1].y) << 16);
        o.w = bf16_rne(acc2[k][2].y);
        *(uint4*)(agg + base) = o;   // base even -> 16B aligned
    }
}

// ---------------------------------------------------------------------------
// Phase A: one dispatch per group; block-uniform layer switch.
// b = local & 7: with round-robin block->XCD dispatch and 8 images == 8 XCDs,
// each XCD only ever touches one image (block_start is always 8-aligned).
// ---------------------------------------------------------------------------
__global__ __launch_bounds__(256, 4) void agg_all(
        const float* __restrict__ x,
        const float4* __restrict__ wT,
        uint2* __restrict__ agg,
        AggArgs a) {
    int bid = blockIdx.x;
    int ci = 0;
    while (ci + 1 < a.n && bid >= a.e[ci + 1].block_start) ci++;
    const ACfg c = a.e[ci];
    int local = bid - c.block_start;
    int b     = local & 7;           // image-per-XCD
    int sblk  = local >> 3;

    const int gsz = (c.layer == 0) ? 196 : (c.layer == 1) ? 49 : 16;
    __shared__ float4 wlds[196];
    for (int t = threadIdx.x; t < gsz; t += 256)
        wlds[t] = wT[c.wt_off + b * gsz + t];
    __syncthreads();

    int pidx = sblk * 256 + (int)threadIdx.x;
    if (pidx >= c.kh * c.qpr) return;
    int h  = pidx / c.qpr;
    int w0 = (pidx - h * c.qpr) * 2;

    const float* __restrict__ xb = x + (size_t)b * (IMG_HW * IMG_HW * 3);
    if (c.layer == 0)      agg_body<14, 14, 32>(c, b, h, w0, xb, wlds, agg);
    else if (c.layer == 1) agg_body<7, 7, 64>(c, b, h, w0, xb, wlds, agg);
    else                   agg_body<4, 4, 128>(c, b, h, w0, xb, wlds, agg);
}

// ---------------------------------------------------------------------------
// Compile-time tap micro-kernel: TH x TW taps, constexpr plane geometry.
// ---------------------------------------------------------------------------
template <int TH, int TW, int KH_, int KW_, int KWP_>
__device__ inline void taps_ct(const uint2* __restrict__ base,
                               int i0, int j0,
                               float4 wh4, float4 ww4,
                               float& a0, float& a1, float& a2) {
    const float* wh = (const float*)&wh4;
    const float* ww = (const float*)&ww4;
    uint2 v[TH][TW];
#pragma unroll
    for (int d = 0; d < TH; ++d) {
        int gi = i0 + d;
        if (gi > KH_ - 1) gi = KH_ - 1;
        const uint2* rp = base + (size_t)gi * KWP_;
#pragma unroll
        for (int e = 0; e < TW; ++e) {
            int gj = j0 + e;
            if (gj > KW_ - 1) gj = KW_ - 1;
            v[d][e] = rp[gj];
        }
    }
#pragma unroll
    for (int d = 0; d < TH; ++d) {
        float r0 = 0.f, r1 = 0.f, r2 = 0.f;
#pragma unroll
        for (int e = 0; e < TW; ++e) {
            uint2 t = v[d][e];
            float c0 = __uint_as_float(t.x << 16);
            float c1 = __uint_as_float(t.x & 0xffff0000u);
            float c2 = __uint_as_float(t.y << 16);
            float w = ww[e];
            r0 = fmaf(w, c0, r0);
            r1 = fmaf(w, c1, r1);
            r2 = fmaf(w, c2, r2);
        }
        a0 = fmaf(wh[d], r0, a0);
        a1 = fmaf(wh[d], r1, a1);
        a2 = fmaf(wh[d], r2, a2);
    }
}

// ---------------------------------------------------------------------------
// if-constexpr recursion over the group's cfgs — fully unrolled rounds.
// ---------------------------------------------------------------------------
template <int C, int CEND, int CSTART>
__device__ inline void do_rounds(const uint2* __restrict__ agg,
                                 const float4* __restrict__ wlds,
                                 const int* __restrict__ ilds,
                                 int bk, int tx, int ty,
                                 float& a0, float& a1, float& a2) {
    if constexpr (C < CEND) {
        constexpr int li  = C - CSTART;
        constexpr int kh  = cKH[C];
        constexpr int kw  = cKW[C];
        constexpr int kwp = ckwp(C);
        constexpr long wso = cwsoff(C, CSTART);
        float4 wh4 = wlds[li * 32 + ty];
        float4 ww4 = wlds[li * 32 + 16 + tx];
        int i0 = ilds[li * 32 + ty];
        int j0 = ilds[li * 32 + 16 + tx];
        const uint2* plane = agg + wso + (size_t)bk * (kh * kwp);
        taps_ct<cMTH[C], cMTW[C], kh, kw, kwp>(plane, i0, j0, wh4, ww4,
                                               a0, a1, a2);
        do_rounds<C + 1, CEND, CSTART>(agg, wlds, ilds, bk, tx, ty,
                                       a0, a1, a2);
    }
}

// ---------------------------------------------------------------------------
// Phase B: static resize. One output px per thread, z = bk (32). Tables in
// LDS (one barrier), all cfg rounds compile-time unrolled.
// ---------------------------------------------------------------------------
template <int CSTART, int CEND>
__global__ __launch_bounds__(256, 4) void resize_static(
        const uint2* __restrict__ agg,
        const float4* __restrict__ wtbl,
        const int* __restrict__ itbl,
        float* __restrict__ out,
        int accumulate) {
    constexpr int NC = CEND - CSTART;
    const int tid = threadIdx.x;
    const int tx = tid & 15;
    const int ty = tid >> 4;
    const int xo = blockIdx.x * 16 + tx;
    const int yo = blockIdx.y * 16 + ty;
    const int bk = blockIdx.z;

    __shared__ float4 wlds[NC * 32];
    __shared__ int    ilds[NC * 32];

    for (int e = tid; e < NC * 32; e += 256) {
        int ci  = e >> 5;
        int r   = e & 31;
        int isW = r >> 4;
        int idx = r & 15;
        int base_o = isW ? (blockIdx.x * 16) : (blockIdx.y * 16);
        int src = (CSTART + ci) * (2 * OUT_HW) + isW * OUT_HW + base_o + idx;
        wlds[ci * 32 + r] = wtbl[src];
        ilds[ci * 32 + r] = itbl[src];
    }
    __syncthreads();

    size_t ob = (((size_t)bk * OUT_HW + yo) * OUT_HW + xo) * 3;
    float a0, a1, a2;
    if (accumulate) {
        a0 = out[ob]; a1 = out[ob + 1]; a2 = out[ob + 2];
    } else {
        a0 = a1 = a2 = 0.f;
    }

    do_rounds<CSTART, CEND, CSTART>(agg, wlds, ilds, bk, tx, ty, a0, a1, a2);

    out[ob + 0] = a0; out[ob + 1] = a1; out[ob + 2] = a2;
}

// ---------------------------------------------------------------------------
// Host launch
// ---------------------------------------------------------------------------
extern "C" void kernel_launch(void* const* d_in, const int* in_sizes, int n_in,
                              void* d_out, int out_size, void* d_ws, size_t ws_size,
                              hipStream_t stream) {
    const float* x   = (const float*)d_in[0];
    const float* wp3 = (const float*)d_in[1];
    const float* wp4 = (const float*)d_in[2];
    const float* wp5 = (const float*)d_in[3];
    float* out = (float*)d_out;
    float4* wtbl = (float4*)d_ws;
    int*    itbl = (int*)((char*)d_ws + WTBL_BYTES);
    float4* wT   = (float4*)((char*)d_ws + WT_OFF_BYTES);
    uint2*  agg  = (uint2*)((char*)d_ws + AGG_OFF_BYTES);

    // Build the 21 configs exactly as the reference does (double precision).
    struct { int stride, size, nscale; double scales[3]; int gh; } layers[3] = {
        {32, 48, 2, {pow(2.0, 1.0 / 3.0), pow(2.0, 2.0 / 3.0), 0.0}, 14},
        {64, 96, 2, {pow(2.0, 1.0 / 3.0), pow(2.0, 2.0 / 3.0), 0.0}, 7},
        {128, 192, 3, {1.0, pow(2.0, 1.0 / 3.0), pow(2.0, 2.0 / 3.0)}, 4},
    };
    const double ars[3] = {0.667, 1.0, 1.5};

    struct HostCfg {
        int kh, kw, kwp, stride, p0, p1, gh, gw, layer, anchor, wt_off;
        int qpr, blocks_per_img;
    } cfg[NCFG];
    TablesArgs ta;
    TrArgs tr;
    int nc = 0, wt_run = 0;
    for (int L = 0; L < 3; ++L) {
        int anchor = 0;
        for (int si = 0; si < layers[L].nscale; ++si) {
            for (int ai = 0; ai < 3; ++ai) {
                double ss = (double)layers[L].size * layers[L].scales[si];
                double sq = pow(ars[ai], 0.5);
                int kh = (int)(ss / sq);
                int kw = (int)(ss * sq);
                HostCfg& e = cfg[nc];
                e.kh = kh; e.kw = kw;
                e.kwp = kw + (kw & 1);
                e.stride = layers[L].stride;
                e.p0 = (int)ceil((double)(kh - layers[L].stride) / 2.0);
                e.p1 = (int)ceil((double)(kw - layers[L].stride) / 2.0);
                e.gh = layers[L].gh; e.gw = layers[L].gh;
                e.layer = L; e.anchor = anchor++;
                e.qpr = e.kwp / 2;
                e.blocks_per_img = (kh * e.qpr + 255) / 256;
                e.wt_off = wt_run;
                int gsz = e.gh * e.gw;
                wt_run += BATCH * gsz;
                ta.kh[nc] = kh; ta.kw[nc] = kw;
                tr.layer[nc] = L; tr.anchor[nc] = e.anchor;
                tr.gsz[nc] = gsz; tr.wt_off[nc] = e.wt_off;
                ++nc;
            }
        }
    }

    init_tables<<<NCFG * 2, 256, 0, stream>>>(wtbl, itbl, ta);
    transpose_w<<<dim3(NCFG, BATCH), 256, 0, stream>>>(wp3, wp4, wp5, wT, tr);

    dim3 rgrid(OUT_HW / 16, OUT_HW / 16, BATCH * KK);

    // Static 3-group schedule: {0..14}, {15..18}, {19..20}.
    auto build = [&](int gstart, int gend, AggArgs& aa) -> int {
        aa.n = 0;
        int ablocks = 0;
        size_t off = 0;
        for (int c = gstart; c < gend; ++c) {
            ACfg& lc = aa.e[aa.n++];
            lc.kh = cfg[c].kh; lc.kw = cfg[c].kw; lc.kwp = cfg[c].kwp;
            lc.p0 = cfg[c].p0; lc.p1 = cfg[c].p1;
            lc.layer = cfg[c].layer;
            lc.qpr = cfg[c].qpr;
            lc.wt_off = cfg[c].wt_off;
            lc.ws_off = (int)off;
            lc.block_start = ablocks;
            lc.blocks_per_img = cfg[c].blocks_per_img;
            ablocks += cfg[c].blocks_per_img * BATCH;
            off += (size_t)cfg[c].kh * cfg[c].kwp * (BATCH * KK);
        }
        return ablocks;
    };

    AggArgs aa;
    int nb;

    nb = build(0, 15, aa);
    agg_all<<<nb, 256, 0, stream>>>(x, wT, agg, aa);
    resize_static<0, 15><<<rgrid, 256, 0, stream>>>(agg, wtbl, itbl, out, 0);

    nb = build(15, 19, aa);
    agg_all<<<nb, 256, 0, stream>>>(x, wT, agg, aa);
    resize_static<15, 19><<<rgrid, 256, 0, stream>>>(agg, wtbl, itbl, out, 1);

    nb = build(19, 21, aa);
    agg_all<<<nb, 256, 0, stream>>>(x, wT, agg, aa);
    resize_static<19, 21><<<rgrid, 256, 0, stream>>>(agg, wtbl, itbl, out, 1);

    (void)in_sizes; (void)n_in; (void)out_size; (void)ws_size;
}